// Round 3
// baseline (250.959 us; speedup 1.0000x reference)
//
#include <hip/hip_runtime.h>
#include <math.h>

// Fixed-size problem: B = 4194304
#define BTOT 4194304
#define TPB  256
#define EPT  16                 // elements per thread
#define CS   (TPB * EPT)        // 4096 elements per chunk/block
#define NCH  (BTOT / CS)        // 1024 chunks
#define CPT  (NCH / TPB)        // 4 chunks per thread in the chunk-scan

// ws layout (floats): 9 arrays of NCH chunk summaries
//  0:Pv 1:Sv 2:Pa 3:Sa 4:sL 5:sq 6:sL2 7:sLq 8:sq2

__constant__ const float kG  = 0.99f;
__constant__ const float kGT = 0.99f * 0.95f;

// ---- hand-rolled grid barrier state (zero-init at module load; the
// sense-reversing design self-resets, so graph replays reuse it safely) ----
__device__ unsigned g_arrive  = 0;
__device__ unsigned g_release = 0;

__device__ __forceinline__ void grid_barrier() {
    __syncthreads();
    if (threadIdx.x == 0) {
        __threadfence();   // publish this block's ws stores at device scope
        unsigned gen = __hip_atomic_load(&g_release, __ATOMIC_RELAXED,
                                         __HIP_MEMORY_SCOPE_AGENT);
        unsigned prev = __hip_atomic_fetch_add(&g_arrive, 1u, __ATOMIC_ACQ_REL,
                                               __HIP_MEMORY_SCOPE_AGENT);
        if (prev == NCH - 1u) {
            // last to arrive: reset count, then flip generation (release
            // orders the reset before the flip)
            __hip_atomic_store(&g_arrive, 0u, __ATOMIC_RELAXED,
                               __HIP_MEMORY_SCOPE_AGENT);
            __hip_atomic_store(&g_release, gen + 1u, __ATOMIC_RELEASE,
                               __HIP_MEMORY_SCOPE_AGENT);
        } else {
            while (__hip_atomic_load(&g_release, __ATOMIC_ACQUIRE,
                                     __HIP_MEMORY_SCOPE_AGENT) == gen) {
                __builtin_amdgcn_s_sleep(2);
            }
        }
    }
    __syncthreads();
}

__device__ __forceinline__ float wave_redf(float x) {
#pragma unroll
    for (int o = 32; o > 0; o >>= 1) x += __shfl_down(x, o);
    return x;
}
__device__ __forceinline__ double wave_redd(double x) {
#pragma unroll
    for (int o = 32; o > 0; o >>= 1) x += __shfl_down(x, o);
    return x;
}

// Hillis-Steele suffix scan over the block on affine pairs (P,S) for both
// recurrences. Entry j ends as the composition of threads j..TPB-1.
__device__ __forceinline__ void block_suffix_scan(
    float pv, float sv, float pa, float sa,
    float* lpv, float* lsv, float* lpa, float* lsa, int j)
{
    lpv[j] = pv; lsv[j] = sv; lpa[j] = pa; lsa[j] = sa;
    __syncthreads();
#pragma unroll
    for (int d = 1; d < TPB; d <<= 1) {
        float cpv = lpv[j], csv = lsv[j], cpa = lpa[j], csa = lsa[j];
        bool has = (j + d) < TPB;
        float qpv = 1.0f, qsv = 0.0f, qpa = 1.0f, qsa = 0.0f;
        if (has) { qpv = lpv[j+d]; qsv = lsv[j+d]; qpa = lpa[j+d]; qsa = lsa[j+d]; }
        __syncthreads();
        if (has) {
            lpv[j] = cpv * qpv; lsv[j] = csv + cpv * qsv;
            lpa[j] = cpa * qpa; lsa[j] = csa + cpa * qsa;
        }
        __syncthreads();
    }
}

// =================== Fused single-pass kernel (fast barrier) ===============
// Phase 1: load inputs ONCE, per-thread summaries, block suffix scan, chunk
//   stats -> ws. rr/dd parked in LDS ([k][j] transposed, conflict-free).
// grid_barrier()  (hand-rolled, device-scope — NOT cg::sync, which costs
//   ~85 µs at 1024 WGs on ROCm)
// Phase 2: every block redundantly scans the 1024 chunk summaries (36 KB,
//   L2-broadcast) -> its own chunk carry + global mean/inv_std.
// Phase 3: finalize from LDS, no input re-read.
__global__ __launch_bounds__(TPB) void ppo_fused(
    const float* __restrict__ r, const float* __restrict__ v,
    const int* __restrict__ mk, float* __restrict__ ws,
    float* __restrict__ outA, float* __restrict__ outV)
{
    const int c = blockIdx.x;
    const int j = threadIdx.x;
    const int base = c * CS + j * EPT;

    __shared__ float lpv[TPB], lsv[TPB], lpa[TPB], lsa[TPB];
    __shared__ float rb[4][5];
    __shared__ double rd[4][2];
    __shared__ float bcast[4];   // 0:carryV(into chunk c) 1:carryA 2:mean 3:inv_std
    __shared__ float s_rr[EPT * TPB];   // [k][j] transposed: bank = j%32
    __shared__ float s_dd[EPT * TPB];

    // ---------------- phase 1: load + summarize (inputs read ONCE) ---------
    unsigned mb = 0;             // mask bits packed: bit k = mask[base+k]
    {
        float rr[EPT], vv[EPT + 1], dd[EPT];
        int mm[EPT];
        const float4* r4 = (const float4*)(r + base);
        const float4* v4 = (const float4*)(v + base);
        const int4*   m4 = (const int4*)(mk + base);
#pragma unroll
        for (int k = 0; k < EPT / 4; ++k) {
            float4 a = r4[k];
            rr[4*k] = a.x; rr[4*k+1] = a.y; rr[4*k+2] = a.z; rr[4*k+3] = a.w;
            float4 b = v4[k];
            vv[4*k] = b.x; vv[4*k+1] = b.y; vv[4*k+2] = b.z; vv[4*k+3] = b.w;
            int4 m = m4[k];
            mm[4*k] = m.x; mm[4*k+1] = m.y; mm[4*k+2] = m.z; mm[4*k+3] = m.w;
        }
        vv[EPT] = (base + EPT < BTOT) ? v[base + EPT] : 0.0f;
#pragma unroll
        for (int k = 0; k < EPT; ++k) {
            mb |= ((unsigned)(mm[k] & 1)) << k;
            float m = (float)mm[k];
            dd[k] = rr[k] + kG * m * vv[k + 1] - vv[k];
        }
        // park rr/dd in LDS for phase 3 (own slots only; no sync needed)
#pragma unroll
        for (int k = 0; k < EPT; ++k) {
            s_rr[k * TPB + j] = rr[k];
            s_dd[k * TPB + j] = dd[k];
        }

        // per-thread affine summaries (reverse, zero carry)
        float pv = 1.0f, sv = 0.0f, pa = 1.0f, sa = 0.0f;
#pragma unroll
        for (int k = EPT - 1; k >= 0; --k) {
            float m = (float)mm[k];
            float av = kG * m, aa = kGT * m;
            sv = rr[k] + av * sv;
            sa = dd[k] + aa * sa;
            pv *= av; pa *= aa;
        }
        block_suffix_scan(pv, sv, pa, sa, lpv, lsv, lpa, lsa, j);
    }

    // per-thread carries within the block (4 regs live across grid sync)
    float CinV = (j + 1 < TPB) ? lsv[j + 1] : 0.0f;
    float QrV  = (j + 1 < TPB) ? lpv[j + 1] : 1.0f;
    float CinA = (j + 1 < TPB) ? lsa[j + 1] : 0.0f;
    float QrA  = (j + 1 < TPB) ? lpa[j + 1] : 1.0f;

    // chunk-local A values + quadratic stats: A = L + q * C_chunk
    {
        float x = CinA, ql = 1.0f;
        float s0 = 0, s1 = 0, s2 = 0, s3 = 0, s4 = 0;
#pragma unroll
        for (int k = EPT - 1; k >= 0; --k) {
            float m = (float)((mb >> k) & 1u);
            float aa = kGT * m;
            x = s_dd[k * TPB + j] + aa * x;
            ql *= aa;
            float q = ql * QrA;
            s0 += x; s1 += q; s2 += x * x; s3 += x * q; s4 += q * q;
        }
        s0 = wave_redf(s0); s1 = wave_redf(s1); s2 = wave_redf(s2);
        s3 = wave_redf(s3); s4 = wave_redf(s4);
        int wid = j >> 6, ln = j & 63;
        if (ln == 0) { rb[wid][0]=s0; rb[wid][1]=s1; rb[wid][2]=s2; rb[wid][3]=s3; rb[wid][4]=s4; }
        __syncthreads();
        if (j == 0) {
            float t0=0,t1=0,t2=0,t3=0,t4=0;
            for (int w = 0; w < 4; ++w) { t0+=rb[w][0]; t1+=rb[w][1]; t2+=rb[w][2]; t3+=rb[w][3]; t4+=rb[w][4]; }
            ws[0*NCH+c] = lpv[0]; ws[1*NCH+c] = lsv[0];
            ws[2*NCH+c] = lpa[0]; ws[3*NCH+c] = lsa[0];
            ws[4*NCH+c] = t0;     ws[5*NCH+c] = t1;     ws[6*NCH+c] = t2;
            ws[7*NCH+c] = t3;     ws[8*NCH+c] = t4;
        }
    }

    grid_barrier();

    // ------- phase 2: redundant chunk-summary scan (identical per block) ---
    float Ccv, Cca, mean, inv;
    {
        float cpv[CPT], csv[CPT], cpa[CPT], csa[CPT];
        {
            float4 t;
            t = *(const float4*)(ws + 0*NCH + 4*j); cpv[0]=t.x; cpv[1]=t.y; cpv[2]=t.z; cpv[3]=t.w;
            t = *(const float4*)(ws + 1*NCH + 4*j); csv[0]=t.x; csv[1]=t.y; csv[2]=t.z; csv[3]=t.w;
            t = *(const float4*)(ws + 2*NCH + 4*j); cpa[0]=t.x; cpa[1]=t.y; cpa[2]=t.z; cpa[3]=t.w;
            t = *(const float4*)(ws + 3*NCH + 4*j); csa[0]=t.x; csa[1]=t.y; csa[2]=t.z; csa[3]=t.w;
        }
        float gpv = 1.0f, gsv = 0.0f, gpa = 1.0f, gsa = 0.0f;
#pragma unroll
        for (int i = CPT - 1; i >= 0; --i) {
            gsv = csv[i] + cpv[i] * gsv; gpv = cpv[i] * gpv;
            gsa = csa[i] + cpa[i] * gsa; gpa = cpa[i] * gpa;
        }

        block_suffix_scan(gpv, gsv, gpa, gsa, lpv, lsv, lpa, lsa, j);

        float Cv = (j + 1 < TPB) ? lsv[j + 1] : 0.0f;
        float Ca = (j + 1 < TPB) ? lsa[j + 1] : 0.0f;

        float sLv[CPT], sqv[CPT], sL2v[CPT], sLqv[CPT], sq2v[CPT];
        {
            float4 t;
            t = *(const float4*)(ws + 4*NCH + 4*j); sLv[0]=t.x;  sLv[1]=t.y;  sLv[2]=t.z;  sLv[3]=t.w;
            t = *(const float4*)(ws + 5*NCH + 4*j); sqv[0]=t.x;  sqv[1]=t.y;  sqv[2]=t.z;  sqv[3]=t.w;
            t = *(const float4*)(ws + 6*NCH + 4*j); sL2v[0]=t.x; sL2v[1]=t.y; sL2v[2]=t.z; sL2v[3]=t.w;
            t = *(const float4*)(ws + 7*NCH + 4*j); sLqv[0]=t.x; sLqv[1]=t.y; sLqv[2]=t.z; sLqv[3]=t.w;
            t = *(const float4*)(ws + 8*NCH + 4*j); sq2v[0]=t.x; sq2v[1]=t.y; sq2v[2]=t.z; sq2v[3]=t.w;
        }
        double dS = 0.0, dS2 = 0.0;
#pragma unroll
        for (int i = CPT - 1; i >= 0; --i) {
            int g = 4*j + i;
            if (g == c) { bcast[0] = Cv; bcast[1] = Ca; }   // carry INTO our chunk
            dS  += (double)(sLv[i]  + Ca * sqv[i]);
            dS2 += (double)(sL2v[i] + 2.0f * Ca * sLqv[i] + Ca * Ca * sq2v[i]);
            Cv = csv[i] + cpv[i] * Cv;
            Ca = csa[i] + cpa[i] * Ca;
        }
        dS = wave_redd(dS); dS2 = wave_redd(dS2);
        int wid = j >> 6, ln = j & 63;
        if (ln == 0) { rd[wid][0] = dS; rd[wid][1] = dS2; }
        __syncthreads();
        if (j == 0) {
            double S  = rd[0][0] + rd[1][0] + rd[2][0] + rd[3][0];
            double S2 = rd[0][1] + rd[1][1] + rd[2][1] + rd[3][1];
            double n = (double)BTOT;
            double m_ = S / n;
            double var = (S2 - S * m_) / (n - 1.0);   // ddof=1
            bcast[2] = (float)m_;
            bcast[3] = (float)(1.0 / sqrt(var));
        }
        __syncthreads();
        Ccv  = bcast[0];
        Cca  = bcast[1];
        mean = bcast[2];
        inv  = bcast[3];
    }

    // ------- phase 3: finalize from LDS (NO input re-read, no big regs) ----
    float xv = CinV + QrV * Ccv;   // true value at this thread's right boundary
    float xa = CinA + QrA * Cca;
    float oA[EPT], oV[EPT];
#pragma unroll
    for (int k = EPT - 1; k >= 0; --k) {
        float m = (float)((mb >> k) & 1u);
        xv = s_rr[k * TPB + j] + kG  * m * xv;
        xa = s_dd[k * TPB + j] + kGT * m * xa;
        oV[k] = xv;
        oA[k] = (xa - mean) * inv;
    }
    float4* a4 = (float4*)(outA + base);
    float4* w4 = (float4*)(outV + base);
#pragma unroll
    for (int k = 0; k < EPT / 4; ++k) {
        a4[k] = make_float4(oA[4*k], oA[4*k+1], oA[4*k+2], oA[4*k+3]);
        w4[k] = make_float4(oV[4*k], oV[4*k+1], oV[4*k+2], oV[4*k+3]);
    }
}

// =================== Fallback path: original K1 + K2 =======================
__global__ __launch_bounds__(TPB) void ppo_k1_summarize(
    const float* __restrict__ r, const float* __restrict__ v,
    const int* __restrict__ mk, float* __restrict__ ws) {
    const int c = blockIdx.x;
    const int j = threadIdx.x;
    const int base = c * CS + j * EPT;

    float rr[EPT], vv[EPT + 1], dd[EPT];
    int mm[EPT];
    const float4* r4 = (const float4*)(r + base);
    const float4* v4 = (const float4*)(v + base);
    const int4*   m4 = (const int4*)(mk + base);
#pragma unroll
    for (int k = 0; k < EPT / 4; ++k) {
        float4 a = r4[k];
        rr[4*k] = a.x; rr[4*k+1] = a.y; rr[4*k+2] = a.z; rr[4*k+3] = a.w;
        float4 b = v4[k];
        vv[4*k] = b.x; vv[4*k+1] = b.y; vv[4*k+2] = b.z; vv[4*k+3] = b.w;
        int4 m = m4[k];
        mm[4*k] = m.x; mm[4*k+1] = m.y; mm[4*k+2] = m.z; mm[4*k+3] = m.w;
    }
    vv[EPT] = (base + EPT < BTOT) ? v[base + EPT] : 0.0f;

#pragma unroll
    for (int k = 0; k < EPT; ++k) {
        float m = (float)mm[k];
        dd[k] = rr[k] + kG * m * vv[k + 1] - vv[k];
    }

    float pv = 1.0f, sv = 0.0f, pa = 1.0f, sa = 0.0f;
#pragma unroll
    for (int k = EPT - 1; k >= 0; --k) {
        float m = (float)mm[k];
        float av = kG * m, aa = kGT * m;
        sv = rr[k] + av * sv;
        sa = dd[k] + aa * sa;
        pv *= av; pa *= aa;
    }

    __shared__ float lpv[TPB], lsv[TPB], lpa[TPB], lsa[TPB];
    block_suffix_scan(pv, sv, pa, sa, lpv, lsv, lpa, lsa, j);

    float CinA = (j + 1 < TPB) ? lsa[j + 1] : 0.0f;
    float QrA  = (j + 1 < TPB) ? lpa[j + 1] : 1.0f;
    float chPv = lpv[0], chSv = lsv[0], chPa = lpa[0], chSa = lsa[0];

    float x = CinA, ql = 1.0f;
    float s0 = 0, s1 = 0, s2 = 0, s3 = 0, s4 = 0;
#pragma unroll
    for (int k = EPT - 1; k >= 0; --k) {
        float m = (float)mm[k];
        float aa = kGT * m;
        x = dd[k] + aa * x;
        ql *= aa;
        float q = ql * QrA;
        s0 += x; s1 += q; s2 += x * x; s3 += x * q; s4 += q * q;
    }
    s0 = wave_redf(s0); s1 = wave_redf(s1); s2 = wave_redf(s2);
    s3 = wave_redf(s3); s4 = wave_redf(s4);
    __shared__ float rb[4][5];
    int wid = j >> 6, ln = j & 63;
    if (ln == 0) { rb[wid][0]=s0; rb[wid][1]=s1; rb[wid][2]=s2; rb[wid][3]=s3; rb[wid][4]=s4; }
    __syncthreads();
    if (j == 0) {
        float t0=0,t1=0,t2=0,t3=0,t4=0;
        for (int w = 0; w < 4; ++w) { t0+=rb[w][0]; t1+=rb[w][1]; t2+=rb[w][2]; t3+=rb[w][3]; t4+=rb[w][4]; }
        ws[0*NCH+c] = chPv; ws[1*NCH+c] = chSv; ws[2*NCH+c] = chPa; ws[3*NCH+c] = chSa;
        ws[4*NCH+c] = t0;   ws[5*NCH+c] = t1;   ws[6*NCH+c] = t2;
        ws[7*NCH+c] = t3;   ws[8*NCH+c] = t4;
    }
}

__global__ __launch_bounds__(TPB) void ppo_k2_finalize(
    const float* __restrict__ r, const float* __restrict__ v,
    const int* __restrict__ mk, const float* __restrict__ ws,
    float* __restrict__ outA, float* __restrict__ outV)
{
    const int c = blockIdx.x;
    const int j = threadIdx.x;
    const int base = c * CS + j * EPT;

    __shared__ float lpv[TPB], lsv[TPB], lpa[TPB], lsa[TPB];
    __shared__ double rd[4][2];
    __shared__ float bcast[4];

    {
        float cpv[CPT], csv[CPT], cpa[CPT], csa[CPT];
        {
            float4 t;
            t = *(const float4*)(ws + 0*NCH + 4*j); cpv[0]=t.x; cpv[1]=t.y; cpv[2]=t.z; cpv[3]=t.w;
            t = *(const float4*)(ws + 1*NCH + 4*j); csv[0]=t.x; csv[1]=t.y; csv[2]=t.z; csv[3]=t.w;
            t = *(const float4*)(ws + 2*NCH + 4*j); cpa[0]=t.x; cpa[1]=t.y; cpa[2]=t.z; cpa[3]=t.w;
            t = *(const float4*)(ws + 3*NCH + 4*j); csa[0]=t.x; csa[1]=t.y; csa[2]=t.z; csa[3]=t.w;
        }
        float gpv = 1.0f, gsv = 0.0f, gpa = 1.0f, gsa = 0.0f;
#pragma unroll
        for (int i = CPT - 1; i >= 0; --i) {
            gsv = csv[i] + cpv[i] * gsv; gpv = cpv[i] * gpv;
            gsa = csa[i] + cpa[i] * gsa; gpa = cpa[i] * gpa;
        }

        block_suffix_scan(gpv, gsv, gpa, gsa, lpv, lsv, lpa, lsa, j);

        float Cv = (j + 1 < TPB) ? lsv[j + 1] : 0.0f;
        float Ca = (j + 1 < TPB) ? lsa[j + 1] : 0.0f;

        float sLv[CPT], sqv[CPT], sL2v[CPT], sLqv[CPT], sq2v[CPT];
        {
            float4 t;
            t = *(const float4*)(ws + 4*NCH + 4*j); sLv[0]=t.x;  sLv[1]=t.y;  sLv[2]=t.z;  sLv[3]=t.w;
            t = *(const float4*)(ws + 5*NCH + 4*j); sqv[0]=t.x;  sqv[1]=t.y;  sqv[2]=t.z;  sqv[3]=t.w;
            t = *(const float4*)(ws + 6*NCH + 4*j); sL2v[0]=t.x; sL2v[1]=t.y; sL2v[2]=t.z; sL2v[3]=t.w;
            t = *(const float4*)(ws + 7*NCH + 4*j); sLqv[0]=t.x; sLqv[1]=t.y; sLqv[2]=t.z; sLqv[3]=t.w;
            t = *(const float4*)(ws + 8*NCH + 4*j); sq2v[0]=t.x; sq2v[1]=t.y; sq2v[2]=t.z; sq2v[3]=t.w;
        }
        double dS = 0.0, dS2 = 0.0;
#pragma unroll
        for (int i = CPT - 1; i >= 0; --i) {
            int g = 4*j + i;
            if (g == c) { bcast[0] = Cv; bcast[1] = Ca; }
            dS  += (double)(sLv[i]  + Ca * sqv[i]);
            dS2 += (double)(sL2v[i] + 2.0f * Ca * sLqv[i] + Ca * Ca * sq2v[i]);
            Cv = csv[i] + cpv[i] * Cv;
            Ca = csa[i] + cpa[i] * Ca;
        }
        dS = wave_redd(dS); dS2 = wave_redd(dS2);
        int wid = j >> 6, ln = j & 63;
        if (ln == 0) { rd[wid][0] = dS; rd[wid][1] = dS2; }
        __syncthreads();
        if (j == 0) {
            double S  = rd[0][0] + rd[1][0] + rd[2][0] + rd[3][0];
            double S2 = rd[0][1] + rd[1][1] + rd[2][1] + rd[3][1];
            double n = (double)BTOT;
            double mean = S / n;
            double var = (S2 - S * mean) / (n - 1.0);
            bcast[2] = (float)mean;
            bcast[3] = (float)(1.0 / sqrt(var));
        }
        __syncthreads();
    }

    float rr[EPT], vv[EPT + 1], dd[EPT];
    int mm[EPT];
    const float4* r4 = (const float4*)(r + base);
    const float4* v4 = (const float4*)(v + base);
    const int4*   m4 = (const int4*)(mk + base);
#pragma unroll
    for (int k = 0; k < EPT / 4; ++k) {
        float4 a = r4[k];
        rr[4*k] = a.x; rr[4*k+1] = a.y; rr[4*k+2] = a.z; rr[4*k+3] = a.w;
        float4 b = v4[k];
        vv[4*k] = b.x; vv[4*k+1] = b.y; vv[4*k+2] = b.z; vv[4*k+3] = b.w;
        int4 m = m4[k];
        mm[4*k] = m.x; mm[4*k+1] = m.y; mm[4*k+2] = m.z; mm[4*k+3] = m.w;
    }
    vv[EPT] = (base + EPT < BTOT) ? v[base + EPT] : 0.0f;
#pragma unroll
    for (int k = 0; k < EPT; ++k) {
        float m = (float)mm[k];
        dd[k] = rr[k] + kG * m * vv[k + 1] - vv[k];
    }

    float pv = 1.0f, sv = 0.0f, pa = 1.0f, sa = 0.0f;
#pragma unroll
    for (int k = EPT - 1; k >= 0; --k) {
        float m = (float)mm[k];
        float av = kG * m, aa = kGT * m;
        sv = rr[k] + av * sv;
        sa = dd[k] + aa * sa;
        pv *= av; pa *= aa;
    }
    block_suffix_scan(pv, sv, pa, sa, lpv, lsv, lpa, lsa, j);

    float CinV = (j + 1 < TPB) ? lsv[j + 1] : 0.0f;
    float QrV  = (j + 1 < TPB) ? lpv[j + 1] : 1.0f;
    float CinA = (j + 1 < TPB) ? lsa[j + 1] : 0.0f;
    float QrA  = (j + 1 < TPB) ? lpa[j + 1] : 1.0f;

    const float Ccv  = bcast[0];
    const float Cca  = bcast[1];
    const float mean = bcast[2];
    const float inv  = bcast[3];

    float xv = CinV + QrV * Ccv;
    float xa = CinA + QrA * Cca;
    float oA[EPT], oV[EPT];
#pragma unroll
    for (int k = EPT - 1; k >= 0; --k) {
        float m = (float)mm[k];
        xv = rr[k] + kG  * m * xv;
        xa = dd[k] + kGT * m * xa;
        oV[k] = xv;
        oA[k] = (xa - mean) * inv;
    }
    float4* a4 = (float4*)(outA + base);
    float4* w4 = (float4*)(outV + base);
#pragma unroll
    for (int k = 0; k < EPT / 4; ++k) {
        a4[k] = make_float4(oA[4*k], oA[4*k+1], oA[4*k+2], oA[4*k+3]);
        w4[k] = make_float4(oV[4*k], oV[4*k+1], oV[4*k+2], oV[4*k+3]);
    }
}

extern "C" void kernel_launch(void* const* d_in, const int* in_sizes, int n_in,
                              void* d_out, int out_size, void* d_ws, size_t ws_size,
                              hipStream_t stream) {
    const float* r  = (const float*)d_in[0];
    const float* v  = (const float*)d_in[1];
    const int*   mk = (const int*)d_in[2];
    float* outA = (float*)d_out;
    float* outV = outA + BTOT;
    float* ws   = (float*)d_ws;

    void* args[6];
    args[0] = (void*)&r;    args[1] = (void*)&v;    args[2] = (void*)&mk;
    args[3] = (void*)&ws;   args[4] = (void*)&outA; args[5] = (void*)&outV;

    // Cooperative launch guarantees co-residency of all 1024 blocks (needed
    // for the hand-rolled barrier); we just don't use cg's slow sync.
    hipError_t e = hipLaunchCooperativeKernel(
        (const void*)ppo_fused, dim3(NCH), dim3(TPB), args, 0, stream);
    if (e != hipSuccess) {
        // Fallback: proven two-kernel path (implicit global sync between them)
        hipLaunchKernelGGL(ppo_k1_summarize, dim3(NCH), dim3(TPB), 0, stream,
                           r, v, mk, ws);
        hipLaunchKernelGGL(ppo_k2_finalize, dim3(NCH), dim3(TPB), 0, stream,
                           r, v, mk, ws, outA, outV);
    }
}

// Round 4
// 175.583 us; speedup vs baseline: 1.4293x; 1.4293x over previous
//
#include <hip/hip_runtime.h>
#include <math.h>

// Fixed-size problem: B = 4194304
#define BTOT 4194304
#define TPB  256
#define EPT  16                 // elements per thread
#define CS   (TPB * EPT)        // 4096 elements per chunk/block
#define NCH  (BTOT / CS)        // 1024 chunks
#define CPT  (NCH / TPB)        // 4 chunks per thread in the chunk-scan

// ws layout (floats): 9 arrays of NCH chunk summaries
//  0:Pv 1:Sv 2:Pa 3:Sa 4:sL 5:sq 6:sL2 7:sLq 8:sq2

__constant__ const float kG  = 0.99f;
__constant__ const float kGT = 0.99f * 0.95f;

// ---- grid barrier state (sense-reversing; self-resets across replays) ----
__device__ unsigned g_arrive  = 0;
__device__ unsigned g_release = 0;

// Agent-scope RELAXED atomic access to ws: write-through / L2-bypassing, so
// cross-XCD visibility needs NO cache-maintenance fences (no buffer_wbl2 /
// buffer_inv — those were the ~100 µs cost of cg::sync and the r3 barrier).
__device__ __forceinline__ void st_ws(float* p, float x) {
    __hip_atomic_store(p, x, __ATOMIC_RELAXED, __HIP_MEMORY_SCOPE_AGENT);
}
__device__ __forceinline__ float ld_ws(const float* p) {
    return __hip_atomic_load(p, __ATOMIC_RELAXED, __HIP_MEMORY_SCOPE_AGENT);
}

__device__ __forceinline__ void grid_barrier_fast() {
    __syncthreads();
    if (threadIdx.x == 0) {
        // drain outstanding (write-through) ws stores; waitcnt only, no cache ops
        __builtin_amdgcn_fence(__ATOMIC_RELEASE, "workgroup");
        unsigned gen = __hip_atomic_load(&g_release, __ATOMIC_RELAXED,
                                         __HIP_MEMORY_SCOPE_AGENT);
        unsigned prev = __hip_atomic_fetch_add(&g_arrive, 1u, __ATOMIC_RELAXED,
                                               __HIP_MEMORY_SCOPE_AGENT);
        if (prev == NCH - 1u) {
            __hip_atomic_store(&g_arrive, 0u, __ATOMIC_RELAXED,
                               __HIP_MEMORY_SCOPE_AGENT);
            __hip_atomic_store(&g_release, gen + 1u, __ATOMIC_RELAXED,
                               __HIP_MEMORY_SCOPE_AGENT);
        } else {
            while (__hip_atomic_load(&g_release, __ATOMIC_RELAXED,
                                     __HIP_MEMORY_SCOPE_AGENT) == gen) {
                __builtin_amdgcn_s_sleep(8);
            }
        }
    }
    __syncthreads();
}

__device__ __forceinline__ float wave_redf(float x) {
#pragma unroll
    for (int o = 32; o > 0; o >>= 1) x += __shfl_down(x, o);
    return x;
}
__device__ __forceinline__ double wave_redd(double x) {
#pragma unroll
    for (int o = 32; o > 0; o >>= 1) x += __shfl_down(x, o);
    return x;
}

// Hillis-Steele suffix scan over the block on affine pairs (P,S) for both
// recurrences. Entry j ends as the composition of threads j..TPB-1.
__device__ __forceinline__ void block_suffix_scan(
    float pv, float sv, float pa, float sa,
    float* lpv, float* lsv, float* lpa, float* lsa, int j)
{
    lpv[j] = pv; lsv[j] = sv; lpa[j] = pa; lsa[j] = sa;
    __syncthreads();
#pragma unroll
    for (int d = 1; d < TPB; d <<= 1) {
        float cpv = lpv[j], csv = lsv[j], cpa = lpa[j], csa = lsa[j];
        bool has = (j + d) < TPB;
        float qpv = 1.0f, qsv = 0.0f, qpa = 1.0f, qsa = 0.0f;
        if (has) { qpv = lpv[j+d]; qsv = lsv[j+d]; qpa = lpa[j+d]; qsa = lsa[j+d]; }
        __syncthreads();
        if (has) {
            lpv[j] = cpv * qpv; lsv[j] = csv + cpv * qsv;
            lpa[j] = cpa * qpa; lsa[j] = csa + cpa * qsa;
        }
        __syncthreads();
    }
}

// =================== Fused single-pass kernel (cache-op-free barrier) ======
__global__ __launch_bounds__(TPB) void ppo_fused(
    const float* __restrict__ r, const float* __restrict__ v,
    const int* __restrict__ mk, float* __restrict__ ws,
    float* __restrict__ outA, float* __restrict__ outV)
{
    const int c = blockIdx.x;
    const int j = threadIdx.x;
    const int base = c * CS + j * EPT;

    __shared__ float lpv[TPB], lsv[TPB], lpa[TPB], lsa[TPB];
    __shared__ float rb[4][5];
    __shared__ double rd[4][2];
    __shared__ float bcast[4];   // 0:carryV(into chunk c) 1:carryA 2:mean 3:inv_std
    __shared__ float s_rr[EPT * TPB];   // [k][j] transposed: bank = j%32
    __shared__ float s_dd[EPT * TPB];

    // ---------------- phase 1: load + summarize (inputs read ONCE) ---------
    unsigned mb = 0;             // mask bits packed: bit k = mask[base+k]
    {
        float rr[EPT], vv[EPT + 1], dd[EPT];
        int mm[EPT];
        const float4* r4 = (const float4*)(r + base);
        const float4* v4 = (const float4*)(v + base);
        const int4*   m4 = (const int4*)(mk + base);
#pragma unroll
        for (int k = 0; k < EPT / 4; ++k) {
            float4 a = r4[k];
            rr[4*k] = a.x; rr[4*k+1] = a.y; rr[4*k+2] = a.z; rr[4*k+3] = a.w;
            float4 b = v4[k];
            vv[4*k] = b.x; vv[4*k+1] = b.y; vv[4*k+2] = b.z; vv[4*k+3] = b.w;
            int4 m = m4[k];
            mm[4*k] = m.x; mm[4*k+1] = m.y; mm[4*k+2] = m.z; mm[4*k+3] = m.w;
        }
        vv[EPT] = (base + EPT < BTOT) ? v[base + EPT] : 0.0f;
#pragma unroll
        for (int k = 0; k < EPT; ++k) {
            mb |= ((unsigned)(mm[k] & 1)) << k;
            float m = (float)mm[k];
            dd[k] = rr[k] + kG * m * vv[k + 1] - vv[k];
        }
        // park rr/dd in LDS for phase 3 (own slots only; no sync needed)
#pragma unroll
        for (int k = 0; k < EPT; ++k) {
            s_rr[k * TPB + j] = rr[k];
            s_dd[k * TPB + j] = dd[k];
        }

        // per-thread affine summaries (reverse, zero carry)
        float pv = 1.0f, sv = 0.0f, pa = 1.0f, sa = 0.0f;
#pragma unroll
        for (int k = EPT - 1; k >= 0; --k) {
            float m = (float)mm[k];
            float av = kG * m, aa = kGT * m;
            sv = rr[k] + av * sv;
            sa = dd[k] + aa * sa;
            pv *= av; pa *= aa;
        }
        block_suffix_scan(pv, sv, pa, sa, lpv, lsv, lpa, lsa, j);
    }

    // per-thread carries within the block (4 regs live across grid sync)
    float CinV = (j + 1 < TPB) ? lsv[j + 1] : 0.0f;
    float QrV  = (j + 1 < TPB) ? lpv[j + 1] : 1.0f;
    float CinA = (j + 1 < TPB) ? lsa[j + 1] : 0.0f;
    float QrA  = (j + 1 < TPB) ? lpa[j + 1] : 1.0f;

    // chunk-local A values + quadratic stats: A = L + q * C_chunk
    {
        float x = CinA, ql = 1.0f;
        float s0 = 0, s1 = 0, s2 = 0, s3 = 0, s4 = 0;
#pragma unroll
        for (int k = EPT - 1; k >= 0; --k) {
            float m = (float)((mb >> k) & 1u);
            float aa = kGT * m;
            x = s_dd[k * TPB + j] + aa * x;
            ql *= aa;
            float q = ql * QrA;
            s0 += x; s1 += q; s2 += x * x; s3 += x * q; s4 += q * q;
        }
        s0 = wave_redf(s0); s1 = wave_redf(s1); s2 = wave_redf(s2);
        s3 = wave_redf(s3); s4 = wave_redf(s4);
        int wid = j >> 6, ln = j & 63;
        if (ln == 0) { rb[wid][0]=s0; rb[wid][1]=s1; rb[wid][2]=s2; rb[wid][3]=s3; rb[wid][4]=s4; }
        __syncthreads();
        if (j == 0) {
            float t0=0,t1=0,t2=0,t3=0,t4=0;
            for (int w = 0; w < 4; ++w) { t0+=rb[w][0]; t1+=rb[w][1]; t2+=rb[w][2]; t3+=rb[w][3]; t4+=rb[w][4]; }
            // write-through atomic stores: globally visible once vmcnt drains,
            // no L2 writeback needed at the barrier
            st_ws(&ws[0*NCH+c], lpv[0]); st_ws(&ws[1*NCH+c], lsv[0]);
            st_ws(&ws[2*NCH+c], lpa[0]); st_ws(&ws[3*NCH+c], lsa[0]);
            st_ws(&ws[4*NCH+c], t0);     st_ws(&ws[5*NCH+c], t1);
            st_ws(&ws[6*NCH+c], t2);     st_ws(&ws[7*NCH+c], t3);
            st_ws(&ws[8*NCH+c], t4);
        }
    }

    grid_barrier_fast();

    // ------- phase 2: redundant chunk-summary scan (identical per block) ---
    // all ws reads are agent-scope relaxed atomics (bypass possibly-stale L2)
    float Ccv, Cca, mean, inv;
    {
        float cpv[CPT], csv[CPT], cpa[CPT], csa[CPT];
#pragma unroll
        for (int i = 0; i < CPT; ++i) {
            cpv[i] = ld_ws(ws + 0*NCH + 4*j + i);
            csv[i] = ld_ws(ws + 1*NCH + 4*j + i);
            cpa[i] = ld_ws(ws + 2*NCH + 4*j + i);
            csa[i] = ld_ws(ws + 3*NCH + 4*j + i);
        }
        float gpv = 1.0f, gsv = 0.0f, gpa = 1.0f, gsa = 0.0f;
#pragma unroll
        for (int i = CPT - 1; i >= 0; --i) {
            gsv = csv[i] + cpv[i] * gsv; gpv = cpv[i] * gpv;
            gsa = csa[i] + cpa[i] * gsa; gpa = cpa[i] * gpa;
        }

        block_suffix_scan(gpv, gsv, gpa, gsa, lpv, lsv, lpa, lsa, j);

        float Cv = (j + 1 < TPB) ? lsv[j + 1] : 0.0f;
        float Ca = (j + 1 < TPB) ? lsa[j + 1] : 0.0f;

        float sLv[CPT], sqv[CPT], sL2v[CPT], sLqv[CPT], sq2v[CPT];
#pragma unroll
        for (int i = 0; i < CPT; ++i) {
            sLv[i]  = ld_ws(ws + 4*NCH + 4*j + i);
            sqv[i]  = ld_ws(ws + 5*NCH + 4*j + i);
            sL2v[i] = ld_ws(ws + 6*NCH + 4*j + i);
            sLqv[i] = ld_ws(ws + 7*NCH + 4*j + i);
            sq2v[i] = ld_ws(ws + 8*NCH + 4*j + i);
        }
        double dS = 0.0, dS2 = 0.0;
#pragma unroll
        for (int i = CPT - 1; i >= 0; --i) {
            int g = 4*j + i;
            if (g == c) { bcast[0] = Cv; bcast[1] = Ca; }   // carry INTO our chunk
            dS  += (double)(sLv[i]  + Ca * sqv[i]);
            dS2 += (double)(sL2v[i] + 2.0f * Ca * sLqv[i] + Ca * Ca * sq2v[i]);
            Cv = csv[i] + cpv[i] * Cv;
            Ca = csa[i] + cpa[i] * Ca;
        }
        dS = wave_redd(dS); dS2 = wave_redd(dS2);
        int wid = j >> 6, ln = j & 63;
        if (ln == 0) { rd[wid][0] = dS; rd[wid][1] = dS2; }
        __syncthreads();
        if (j == 0) {
            double S  = rd[0][0] + rd[1][0] + rd[2][0] + rd[3][0];
            double S2 = rd[0][1] + rd[1][1] + rd[2][1] + rd[3][1];
            double n = (double)BTOT;
            double m_ = S / n;
            double var = (S2 - S * m_) / (n - 1.0);   // ddof=1
            bcast[2] = (float)m_;
            bcast[3] = (float)(1.0 / sqrt(var));
        }
        __syncthreads();
        Ccv  = bcast[0];
        Cca  = bcast[1];
        mean = bcast[2];
        inv  = bcast[3];
    }

    // ------- phase 3: finalize from LDS (NO input re-read, no big regs) ----
    float xv = CinV + QrV * Ccv;   // true value at this thread's right boundary
    float xa = CinA + QrA * Cca;
    float oA[EPT], oV[EPT];
#pragma unroll
    for (int k = EPT - 1; k >= 0; --k) {
        float m = (float)((mb >> k) & 1u);
        xv = s_rr[k * TPB + j] + kG  * m * xv;
        xa = s_dd[k * TPB + j] + kGT * m * xa;
        oV[k] = xv;
        oA[k] = (xa - mean) * inv;
    }
    float4* a4 = (float4*)(outA + base);
    float4* w4 = (float4*)(outV + base);
#pragma unroll
    for (int k = 0; k < EPT / 4; ++k) {
        a4[k] = make_float4(oA[4*k], oA[4*k+1], oA[4*k+2], oA[4*k+3]);
        w4[k] = make_float4(oV[4*k], oV[4*k+1], oV[4*k+2], oV[4*k+3]);
    }
}

// =================== Fallback path: original K1 + K2 =======================
__global__ __launch_bounds__(TPB) void ppo_k1_summarize(
    const float* __restrict__ r, const float* __restrict__ v,
    const int* __restrict__ mk, float* __restrict__ ws) {
    const int c = blockIdx.x;
    const int j = threadIdx.x;
    const int base = c * CS + j * EPT;

    float rr[EPT], vv[EPT + 1], dd[EPT];
    int mm[EPT];
    const float4* r4 = (const float4*)(r + base);
    const float4* v4 = (const float4*)(v + base);
    const int4*   m4 = (const int4*)(mk + base);
#pragma unroll
    for (int k = 0; k < EPT / 4; ++k) {
        float4 a = r4[k];
        rr[4*k] = a.x; rr[4*k+1] = a.y; rr[4*k+2] = a.z; rr[4*k+3] = a.w;
        float4 b = v4[k];
        vv[4*k] = b.x; vv[4*k+1] = b.y; vv[4*k+2] = b.z; vv[4*k+3] = b.w;
        int4 m = m4[k];
        mm[4*k] = m.x; mm[4*k+1] = m.y; mm[4*k+2] = m.z; mm[4*k+3] = m.w;
    }
    vv[EPT] = (base + EPT < BTOT) ? v[base + EPT] : 0.0f;

#pragma unroll
    for (int k = 0; k < EPT; ++k) {
        float m = (float)mm[k];
        dd[k] = rr[k] + kG * m * vv[k + 1] - vv[k];
    }

    float pv = 1.0f, sv = 0.0f, pa = 1.0f, sa = 0.0f;
#pragma unroll
    for (int k = EPT - 1; k >= 0; --k) {
        float m = (float)mm[k];
        float av = kG * m, aa = kGT * m;
        sv = rr[k] + av * sv;
        sa = dd[k] + aa * sa;
        pv *= av; pa *= aa;
    }

    __shared__ float lpv[TPB], lsv[TPB], lpa[TPB], lsa[TPB];
    block_suffix_scan(pv, sv, pa, sa, lpv, lsv, lpa, lsa, j);

    float CinA = (j + 1 < TPB) ? lsa[j + 1] : 0.0f;
    float QrA  = (j + 1 < TPB) ? lpa[j + 1] : 1.0f;
    float chPv = lpv[0], chSv = lsv[0], chPa = lpa[0], chSa = lsa[0];

    float x = CinA, ql = 1.0f;
    float s0 = 0, s1 = 0, s2 = 0, s3 = 0, s4 = 0;
#pragma unroll
    for (int k = EPT - 1; k >= 0; --k) {
        float m = (float)mm[k];
        float aa = kGT * m;
        x = dd[k] + aa * x;
        ql *= aa;
        float q = ql * QrA;
        s0 += x; s1 += q; s2 += x * x; s3 += x * q; s4 += q * q;
    }
    s0 = wave_redf(s0); s1 = wave_redf(s1); s2 = wave_redf(s2);
    s3 = wave_redf(s3); s4 = wave_redf(s4);
    __shared__ float rb[4][5];
    int wid = j >> 6, ln = j & 63;
    if (ln == 0) { rb[wid][0]=s0; rb[wid][1]=s1; rb[wid][2]=s2; rb[wid][3]=s3; rb[wid][4]=s4; }
    __syncthreads();
    if (j == 0) {
        float t0=0,t1=0,t2=0,t3=0,t4=0;
        for (int w = 0; w < 4; ++w) { t0+=rb[w][0]; t1+=rb[w][1]; t2+=rb[w][2]; t3+=rb[w][3]; t4+=rb[w][4]; }
        ws[0*NCH+c] = chPv; ws[1*NCH+c] = chSv; ws[2*NCH+c] = chPa; ws[3*NCH+c] = chSa;
        ws[4*NCH+c] = t0;   ws[5*NCH+c] = t1;   ws[6*NCH+c] = t2;
        ws[7*NCH+c] = t3;   ws[8*NCH+c] = t4;
    }
}

__global__ __launch_bounds__(TPB) void ppo_k2_finalize(
    const float* __restrict__ r, const float* __restrict__ v,
    const int* __restrict__ mk, const float* __restrict__ ws,
    float* __restrict__ outA, float* __restrict__ outV)
{
    const int c = blockIdx.x;
    const int j = threadIdx.x;
    const int base = c * CS + j * EPT;

    __shared__ float lpv[TPB], lsv[TPB], lpa[TPB], lsa[TPB];
    __shared__ double rd[4][2];
    __shared__ float bcast[4];

    {
        float cpv[CPT], csv[CPT], cpa[CPT], csa[CPT];
        {
            float4 t;
            t = *(const float4*)(ws + 0*NCH + 4*j); cpv[0]=t.x; cpv[1]=t.y; cpv[2]=t.z; cpv[3]=t.w;
            t = *(const float4*)(ws + 1*NCH + 4*j); csv[0]=t.x; csv[1]=t.y; csv[2]=t.z; csv[3]=t.w;
            t = *(const float4*)(ws + 2*NCH + 4*j); cpa[0]=t.x; cpa[1]=t.y; cpa[2]=t.z; cpa[3]=t.w;
            t = *(const float4*)(ws + 3*NCH + 4*j); csa[0]=t.x; csa[1]=t.y; csa[2]=t.z; csa[3]=t.w;
        }
        float gpv = 1.0f, gsv = 0.0f, gpa = 1.0f, gsa = 0.0f;
#pragma unroll
        for (int i = CPT - 1; i >= 0; --i) {
            gsv = csv[i] + cpv[i] * gsv; gpv = cpv[i] * gpv;
            gsa = csa[i] + cpa[i] * gsa; gpa = cpa[i] * gpa;
        }

        block_suffix_scan(gpv, gsv, gpa, gsa, lpv, lsv, lpa, lsa, j);

        float Cv = (j + 1 < TPB) ? lsv[j + 1] : 0.0f;
        float Ca = (j + 1 < TPB) ? lsa[j + 1] : 0.0f;

        float sLv[CPT], sqv[CPT], sL2v[CPT], sLqv[CPT], sq2v[CPT];
        {
            float4 t;
            t = *(const float4*)(ws + 4*NCH + 4*j); sLv[0]=t.x;  sLv[1]=t.y;  sLv[2]=t.z;  sLv[3]=t.w;
            t = *(const float4*)(ws + 5*NCH + 4*j); sqv[0]=t.x;  sqv[1]=t.y;  sqv[2]=t.z;  sqv[3]=t.w;
            t = *(const float4*)(ws + 6*NCH + 4*j); sL2v[0]=t.x; sL2v[1]=t.y; sL2v[2]=t.z; sL2v[3]=t.w;
            t = *(const float4*)(ws + 7*NCH + 4*j); sLqv[0]=t.x; sLqv[1]=t.y; sLqv[2]=t.z; sLqv[3]=t.w;
            t = *(const float4*)(ws + 8*NCH + 4*j); sq2v[0]=t.x; sq2v[1]=t.y; sq2v[2]=t.z; sq2v[3]=t.w;
        }
        double dS = 0.0, dS2 = 0.0;
#pragma unroll
        for (int i = CPT - 1; i >= 0; --i) {
            int g = 4*j + i;
            if (g == c) { bcast[0] = Cv; bcast[1] = Ca; }
            dS  += (double)(sLv[i]  + Ca * sqv[i]);
            dS2 += (double)(sL2v[i] + 2.0f * Ca * sLqv[i] + Ca * Ca * sq2v[i]);
            Cv = csv[i] + cpv[i] * Cv;
            Ca = csa[i] + cpa[i] * Ca;
        }
        dS = wave_redd(dS); dS2 = wave_redd(dS2);
        int wid = j >> 6, ln = j & 63;
        if (ln == 0) { rd[wid][0] = dS; rd[wid][1] = dS2; }
        __syncthreads();
        if (j == 0) {
            double S  = rd[0][0] + rd[1][0] + rd[2][0] + rd[3][0];
            double S2 = rd[0][1] + rd[1][1] + rd[2][1] + rd[3][1];
            double n = (double)BTOT;
            double mean = S / n;
            double var = (S2 - S * mean) / (n - 1.0);
            bcast[2] = (float)mean;
            bcast[3] = (float)(1.0 / sqrt(var));
        }
        __syncthreads();
    }

    float rr[EPT], vv[EPT + 1], dd[EPT];
    int mm[EPT];
    const float4* r4 = (const float4*)(r + base);
    const float4* v4 = (const float4*)(v + base);
    const int4*   m4 = (const int4*)(mk + base);
#pragma unroll
    for (int k = 0; k < EPT / 4; ++k) {
        float4 a = r4[k];
        rr[4*k] = a.x; rr[4*k+1] = a.y; rr[4*k+2] = a.z; rr[4*k+3] = a.w;
        float4 b = v4[k];
        vv[4*k] = b.x; vv[4*k+1] = b.y; vv[4*k+2] = b.z; vv[4*k+3] = b.w;
        int4 m = m4[k];
        mm[4*k] = m.x; mm[4*k+1] = m.y; mm[4*k+2] = m.z; mm[4*k+3] = m.w;
    }
    vv[EPT] = (base + EPT < BTOT) ? v[base + EPT] : 0.0f;
#pragma unroll
    for (int k = 0; k < EPT; ++k) {
        float m = (float)mm[k];
        dd[k] = rr[k] + kG * m * vv[k + 1] - vv[k];
    }

    float pv = 1.0f, sv = 0.0f, pa = 1.0f, sa = 0.0f;
#pragma unroll
    for (int k = EPT - 1; k >= 0; --k) {
        float m = (float)mm[k];
        float av = kG * m, aa = kGT * m;
        sv = rr[k] + av * sv;
        sa = dd[k] + aa * sa;
        pv *= av; pa *= aa;
    }
    block_suffix_scan(pv, sv, pa, sa, lpv, lsv, lpa, lsa, j);

    float CinV = (j + 1 < TPB) ? lsv[j + 1] : 0.0f;
    float QrV  = (j + 1 < TPB) ? lpv[j + 1] : 1.0f;
    float CinA = (j + 1 < TPB) ? lsa[j + 1] : 0.0f;
    float QrA  = (j + 1 < TPB) ? lpa[j + 1] : 1.0f;

    const float Ccv  = bcast[0];
    const float Cca  = bcast[1];
    const float mean = bcast[2];
    const float inv  = bcast[3];

    float xv = CinV + QrV * Ccv;
    float xa = CinA + QrA * Cca;
    float oA[EPT], oV[EPT];
#pragma unroll
    for (int k = EPT - 1; k >= 0; --k) {
        float m = (float)mm[k];
        xv = rr[k] + kG  * m * xv;
        xa = dd[k] + kGT * m * xa;
        oV[k] = xv;
        oA[k] = (xa - mean) * inv;
    }
    float4* a4 = (float4*)(outA + base);
    float4* w4 = (float4*)(outV + base);
#pragma unroll
    for (int k = 0; k < EPT / 4; ++k) {
        a4[k] = make_float4(oA[4*k], oA[4*k+1], oA[4*k+2], oA[4*k+3]);
        w4[k] = make_float4(oV[4*k], oV[4*k+1], oV[4*k+2], oV[4*k+3]);
    }
}

extern "C" void kernel_launch(void* const* d_in, const int* in_sizes, int n_in,
                              void* d_out, int out_size, void* d_ws, size_t ws_size,
                              hipStream_t stream) {
    const float* r  = (const float*)d_in[0];
    const float* v  = (const float*)d_in[1];
    const int*   mk = (const int*)d_in[2];
    float* outA = (float*)d_out;
    float* outV = outA + BTOT;
    float* ws   = (float*)d_ws;

    void* args[6];
    args[0] = (void*)&r;    args[1] = (void*)&v;    args[2] = (void*)&mk;
    args[3] = (void*)&ws;   args[4] = (void*)&outA; args[5] = (void*)&outV;

    // Cooperative launch guarantees co-residency of all 1024 blocks (needed
    // for the hand-rolled barrier); we just don't use cg's slow sync.
    hipError_t e = hipLaunchCooperativeKernel(
        (const void*)ppo_fused, dim3(NCH), dim3(TPB), args, 0, stream);
    if (e != hipSuccess) {
        // Fallback: proven two-kernel path (implicit global sync between them)
        hipLaunchKernelGGL(ppo_k1_summarize, dim3(NCH), dim3(TPB), 0, stream,
                           r, v, mk, ws);
        hipLaunchKernelGGL(ppo_k2_finalize, dim3(NCH), dim3(TPB), 0, stream,
                           r, v, mk, ws, outA, outV);
    }
}

// Round 5
// 144.899 us; speedup vs baseline: 1.7320x; 1.2118x over previous
//
#include <hip/hip_runtime.h>
#include <math.h>

// Fixed-size problem: B = 4194304
#define BTOT 4194304
#define TPB  256
#define EPT  16                 // elements per thread
#define CS   (TPB * EPT)        // 4096 elements per chunk/block
#define NCH  (BTOT / CS)        // 1024 chunks
#define CPT  (NCH / TPB)        // 4 chunks per thread in the chunk-scan

// ws layout (floats): 9 arrays of NCH chunk summaries
//  0:Pv 1:Sv 2:Pa 3:Sa 4:sL 5:sq 6:sL2 7:sLq 8:sq2

__constant__ const float kG  = 0.99f;
__constant__ const float kGT = 0.99f * 0.95f;

// ---- grid barrier state (sense-reversing; self-resets across replays) ----
// Arrival is a 64-leaf tree: each leaf counter sits on its own 256 B line so
// leaf RMWs proceed in parallel at the coherence point. This replaces 1024
// serialized same-line fetch_adds (~60 µs measured in r4) with ~16+64.
#define NLEAF       64
#define LEAF_STRIDE 64          // 64 uints = 256 B per leaf line
__device__ unsigned g_leaf[NLEAF * LEAF_STRIDE];   // zero-init
__device__ unsigned g_root    = 0;
__device__ unsigned g_release = 0;

// Agent-scope RELAXED atomic access to ws: write-through / L2-bypassing, so
// cross-XCD visibility needs NO cache-maintenance fences (no buffer_wbl2 /
// buffer_inv — those were the ~100 µs cost of cg::sync and the r3 barrier).
__device__ __forceinline__ void st_ws(float* p, float x) {
    __hip_atomic_store(p, x, __ATOMIC_RELAXED, __HIP_MEMORY_SCOPE_AGENT);
}
__device__ __forceinline__ float ld_ws(const float* p) {
    return __hip_atomic_load(p, __ATOMIC_RELAXED, __HIP_MEMORY_SCOPE_AGENT);
}

__device__ __forceinline__ void grid_barrier_tree(int c) {
    __syncthreads();
    if (threadIdx.x == 0) {
        // drain outstanding (write-through) ws stores; waitcnt only, no cache ops
        __builtin_amdgcn_fence(__ATOMIC_RELEASE, "workgroup");
        unsigned gen = __hip_atomic_load(&g_release, __ATOMIC_RELAXED,
                                         __HIP_MEMORY_SCOPE_AGENT);
        unsigned* leaf = &g_leaf[(c & (NLEAF - 1)) * LEAF_STRIDE];
        unsigned prev = __hip_atomic_fetch_add(leaf, 1u, __ATOMIC_RELAXED,
                                               __HIP_MEMORY_SCOPE_AGENT);
        bool last_overall = false;
        if (prev == (NCH / NLEAF) - 1u) {
            unsigned prev2 = __hip_atomic_fetch_add(&g_root, 1u, __ATOMIC_RELAXED,
                                                    __HIP_MEMORY_SCOPE_AGENT);
            last_overall = (prev2 == NLEAF - 1u);
        }
        if (last_overall) {
            // all 1024 arrived: reset tree, then flip generation. Within this
            // launch nobody reads the counters after arrival; across launches
            // the kernel boundary orders reset before next-launch arrivals.
            for (int i = 0; i < NLEAF; ++i)
                __hip_atomic_store(&g_leaf[i * LEAF_STRIDE], 0u,
                                   __ATOMIC_RELAXED, __HIP_MEMORY_SCOPE_AGENT);
            __hip_atomic_store(&g_root, 0u, __ATOMIC_RELAXED,
                               __HIP_MEMORY_SCOPE_AGENT);
            __hip_atomic_store(&g_release, gen + 1u, __ATOMIC_RELAXED,
                               __HIP_MEMORY_SCOPE_AGENT);
        } else {
            while (__hip_atomic_load(&g_release, __ATOMIC_RELAXED,
                                     __HIP_MEMORY_SCOPE_AGENT) == gen) {
                __builtin_amdgcn_s_sleep(8);
            }
        }
    }
    __syncthreads();
}

__device__ __forceinline__ float wave_redf(float x) {
#pragma unroll
    for (int o = 32; o > 0; o >>= 1) x += __shfl_down(x, o);
    return x;
}
__device__ __forceinline__ double wave_redd(double x) {
#pragma unroll
    for (int o = 32; o > 0; o >>= 1) x += __shfl_down(x, o);
    return x;
}

// Hillis-Steele suffix scan over the block on affine pairs (P,S) for both
// recurrences. Entry j ends as the composition of threads j..TPB-1.
__device__ __forceinline__ void block_suffix_scan(
    float pv, float sv, float pa, float sa,
    float* lpv, float* lsv, float* lpa, float* lsa, int j)
{
    lpv[j] = pv; lsv[j] = sv; lpa[j] = pa; lsa[j] = sa;
    __syncthreads();
#pragma unroll
    for (int d = 1; d < TPB; d <<= 1) {
        float cpv = lpv[j], csv = lsv[j], cpa = lpa[j], csa = lsa[j];
        bool has = (j + d) < TPB;
        float qpv = 1.0f, qsv = 0.0f, qpa = 1.0f, qsa = 0.0f;
        if (has) { qpv = lpv[j+d]; qsv = lsv[j+d]; qpa = lpa[j+d]; qsa = lsa[j+d]; }
        __syncthreads();
        if (has) {
            lpv[j] = cpv * qpv; lsv[j] = csv + cpv * qsv;
            lpa[j] = cpa * qpa; lsa[j] = csa + cpa * qsa;
        }
        __syncthreads();
    }
}

// =================== Fused single-pass kernel (tree barrier) ===============
__global__ __launch_bounds__(TPB) void ppo_fused(
    const float* __restrict__ r, const float* __restrict__ v,
    const int* __restrict__ mk, float* __restrict__ ws,
    float* __restrict__ outA, float* __restrict__ outV)
{
    const int c = blockIdx.x;
    const int j = threadIdx.x;
    const int base = c * CS + j * EPT;

    __shared__ float lpv[TPB], lsv[TPB], lpa[TPB], lsa[TPB];
    __shared__ float rb[4][5];
    __shared__ double rd[4][2];
    __shared__ float bcast[4];   // 0:carryV(into chunk c) 1:carryA 2:mean 3:inv_std
    __shared__ float s_rr[EPT * TPB];   // [k][j] transposed: bank = j%32
    __shared__ float s_dd[EPT * TPB];

    // ---------------- phase 1: load + summarize (inputs read ONCE) ---------
    unsigned mb = 0;             // mask bits packed: bit k = mask[base+k]
    {
        float rr[EPT], vv[EPT + 1], dd[EPT];
        int mm[EPT];
        const float4* r4 = (const float4*)(r + base);
        const float4* v4 = (const float4*)(v + base);
        const int4*   m4 = (const int4*)(mk + base);
#pragma unroll
        for (int k = 0; k < EPT / 4; ++k) {
            float4 a = r4[k];
            rr[4*k] = a.x; rr[4*k+1] = a.y; rr[4*k+2] = a.z; rr[4*k+3] = a.w;
            float4 b = v4[k];
            vv[4*k] = b.x; vv[4*k+1] = b.y; vv[4*k+2] = b.z; vv[4*k+3] = b.w;
            int4 m = m4[k];
            mm[4*k] = m.x; mm[4*k+1] = m.y; mm[4*k+2] = m.z; mm[4*k+3] = m.w;
        }
        vv[EPT] = (base + EPT < BTOT) ? v[base + EPT] : 0.0f;
#pragma unroll
        for (int k = 0; k < EPT; ++k) {
            mb |= ((unsigned)(mm[k] & 1)) << k;
            float m = (float)mm[k];
            dd[k] = rr[k] + kG * m * vv[k + 1] - vv[k];
        }
        // park rr/dd in LDS for phase 3 (own slots only; no sync needed)
#pragma unroll
        for (int k = 0; k < EPT; ++k) {
            s_rr[k * TPB + j] = rr[k];
            s_dd[k * TPB + j] = dd[k];
        }

        // per-thread affine summaries (reverse, zero carry)
        float pv = 1.0f, sv = 0.0f, pa = 1.0f, sa = 0.0f;
#pragma unroll
        for (int k = EPT - 1; k >= 0; --k) {
            float m = (float)mm[k];
            float av = kG * m, aa = kGT * m;
            sv = rr[k] + av * sv;
            sa = dd[k] + aa * sa;
            pv *= av; pa *= aa;
        }
        block_suffix_scan(pv, sv, pa, sa, lpv, lsv, lpa, lsa, j);
    }

    // per-thread carries within the block (4 regs live across grid sync)
    float CinV = (j + 1 < TPB) ? lsv[j + 1] : 0.0f;
    float QrV  = (j + 1 < TPB) ? lpv[j + 1] : 1.0f;
    float CinA = (j + 1 < TPB) ? lsa[j + 1] : 0.0f;
    float QrA  = (j + 1 < TPB) ? lpa[j + 1] : 1.0f;

    // chunk-local A values + quadratic stats: A = L + q * C_chunk
    {
        float x = CinA, ql = 1.0f;
        float s0 = 0, s1 = 0, s2 = 0, s3 = 0, s4 = 0;
#pragma unroll
        for (int k = EPT - 1; k >= 0; --k) {
            float m = (float)((mb >> k) & 1u);
            float aa = kGT * m;
            x = s_dd[k * TPB + j] + aa * x;
            ql *= aa;
            float q = ql * QrA;
            s0 += x; s1 += q; s2 += x * x; s3 += x * q; s4 += q * q;
        }
        s0 = wave_redf(s0); s1 = wave_redf(s1); s2 = wave_redf(s2);
        s3 = wave_redf(s3); s4 = wave_redf(s4);
        int wid = j >> 6, ln = j & 63;
        if (ln == 0) { rb[wid][0]=s0; rb[wid][1]=s1; rb[wid][2]=s2; rb[wid][3]=s3; rb[wid][4]=s4; }
        __syncthreads();
        if (j == 0) {
            float t0=0,t1=0,t2=0,t3=0,t4=0;
            for (int w = 0; w < 4; ++w) { t0+=rb[w][0]; t1+=rb[w][1]; t2+=rb[w][2]; t3+=rb[w][3]; t4+=rb[w][4]; }
            // write-through atomic stores: globally visible once vmcnt drains,
            // no L2 writeback needed at the barrier
            st_ws(&ws[0*NCH+c], lpv[0]); st_ws(&ws[1*NCH+c], lsv[0]);
            st_ws(&ws[2*NCH+c], lpa[0]); st_ws(&ws[3*NCH+c], lsa[0]);
            st_ws(&ws[4*NCH+c], t0);     st_ws(&ws[5*NCH+c], t1);
            st_ws(&ws[6*NCH+c], t2);     st_ws(&ws[7*NCH+c], t3);
            st_ws(&ws[8*NCH+c], t4);
        }
    }

    grid_barrier_tree(c);

    // ------- phase 2: redundant chunk-summary scan (identical per block) ---
    // all ws reads are agent-scope relaxed atomics (bypass possibly-stale L2)
    float Ccv, Cca, mean, inv;
    {
        float cpv[CPT], csv[CPT], cpa[CPT], csa[CPT];
#pragma unroll
        for (int i = 0; i < CPT; ++i) {
            cpv[i] = ld_ws(ws + 0*NCH + 4*j + i);
            csv[i] = ld_ws(ws + 1*NCH + 4*j + i);
            cpa[i] = ld_ws(ws + 2*NCH + 4*j + i);
            csa[i] = ld_ws(ws + 3*NCH + 4*j + i);
        }
        float gpv = 1.0f, gsv = 0.0f, gpa = 1.0f, gsa = 0.0f;
#pragma unroll
        for (int i = CPT - 1; i >= 0; --i) {
            gsv = csv[i] + cpv[i] * gsv; gpv = cpv[i] * gpv;
            gsa = csa[i] + cpa[i] * gsa; gpa = cpa[i] * gpa;
        }

        block_suffix_scan(gpv, gsv, gpa, gsa, lpv, lsv, lpa, lsa, j);

        float Cv = (j + 1 < TPB) ? lsv[j + 1] : 0.0f;
        float Ca = (j + 1 < TPB) ? lsa[j + 1] : 0.0f;

        float sLv[CPT], sqv[CPT], sL2v[CPT], sLqv[CPT], sq2v[CPT];
#pragma unroll
        for (int i = 0; i < CPT; ++i) {
            sLv[i]  = ld_ws(ws + 4*NCH + 4*j + i);
            sqv[i]  = ld_ws(ws + 5*NCH + 4*j + i);
            sL2v[i] = ld_ws(ws + 6*NCH + 4*j + i);
            sLqv[i] = ld_ws(ws + 7*NCH + 4*j + i);
            sq2v[i] = ld_ws(ws + 8*NCH + 4*j + i);
        }
        double dS = 0.0, dS2 = 0.0;
#pragma unroll
        for (int i = CPT - 1; i >= 0; --i) {
            int g = 4*j + i;
            if (g == c) { bcast[0] = Cv; bcast[1] = Ca; }   // carry INTO our chunk
            dS  += (double)(sLv[i]  + Ca * sqv[i]);
            dS2 += (double)(sL2v[i] + 2.0f * Ca * sLqv[i] + Ca * Ca * sq2v[i]);
            Cv = csv[i] + cpv[i] * Cv;
            Ca = csa[i] + cpa[i] * Ca;
        }
        dS = wave_redd(dS); dS2 = wave_redd(dS2);
        int wid = j >> 6, ln = j & 63;
        if (ln == 0) { rd[wid][0] = dS; rd[wid][1] = dS2; }
        __syncthreads();
        if (j == 0) {
            double S  = rd[0][0] + rd[1][0] + rd[2][0] + rd[3][0];
            double S2 = rd[0][1] + rd[1][1] + rd[2][1] + rd[3][1];
            double n = (double)BTOT;
            double m_ = S / n;
            double var = (S2 - S * m_) / (n - 1.0);   // ddof=1
            bcast[2] = (float)m_;
            bcast[3] = (float)(1.0 / sqrt(var));
        }
        __syncthreads();
        Ccv  = bcast[0];
        Cca  = bcast[1];
        mean = bcast[2];
        inv  = bcast[3];
    }

    // ------- phase 3: finalize from LDS (NO input re-read, no big regs) ----
    float xv = CinV + QrV * Ccv;   // true value at this thread's right boundary
    float xa = CinA + QrA * Cca;
    float oA[EPT], oV[EPT];
#pragma unroll
    for (int k = EPT - 1; k >= 0; --k) {
        float m = (float)((mb >> k) & 1u);
        xv = s_rr[k * TPB + j] + kG  * m * xv;
        xa = s_dd[k * TPB + j] + kGT * m * xa;
        oV[k] = xv;
        oA[k] = (xa - mean) * inv;
    }
    float4* a4 = (float4*)(outA + base);
    float4* w4 = (float4*)(outV + base);
#pragma unroll
    for (int k = 0; k < EPT / 4; ++k) {
        a4[k] = make_float4(oA[4*k], oA[4*k+1], oA[4*k+2], oA[4*k+3]);
        w4[k] = make_float4(oV[4*k], oV[4*k+1], oV[4*k+2], oV[4*k+3]);
    }
}

// =================== Fallback path: original K1 + K2 =======================
__global__ __launch_bounds__(TPB) void ppo_k1_summarize(
    const float* __restrict__ r, const float* __restrict__ v,
    const int* __restrict__ mk, float* __restrict__ ws) {
    const int c = blockIdx.x;
    const int j = threadIdx.x;
    const int base = c * CS + j * EPT;

    float rr[EPT], vv[EPT + 1], dd[EPT];
    int mm[EPT];
    const float4* r4 = (const float4*)(r + base);
    const float4* v4 = (const float4*)(v + base);
    const int4*   m4 = (const int4*)(mk + base);
#pragma unroll
    for (int k = 0; k < EPT / 4; ++k) {
        float4 a = r4[k];
        rr[4*k] = a.x; rr[4*k+1] = a.y; rr[4*k+2] = a.z; rr[4*k+3] = a.w;
        float4 b = v4[k];
        vv[4*k] = b.x; vv[4*k+1] = b.y; vv[4*k+2] = b.z; vv[4*k+3] = b.w;
        int4 m = m4[k];
        mm[4*k] = m.x; mm[4*k+1] = m.y; mm[4*k+2] = m.z; mm[4*k+3] = m.w;
    }
    vv[EPT] = (base + EPT < BTOT) ? v[base + EPT] : 0.0f;

#pragma unroll
    for (int k = 0; k < EPT; ++k) {
        float m = (float)mm[k];
        dd[k] = rr[k] + kG * m * vv[k + 1] - vv[k];
    }

    float pv = 1.0f, sv = 0.0f, pa = 1.0f, sa = 0.0f;
#pragma unroll
    for (int k = EPT - 1; k >= 0; --k) {
        float m = (float)mm[k];
        float av = kG * m, aa = kGT * m;
        sv = rr[k] + av * sv;
        sa = dd[k] + aa * sa;
        pv *= av; pa *= aa;
    }

    __shared__ float lpv[TPB], lsv[TPB], lpa[TPB], lsa[TPB];
    block_suffix_scan(pv, sv, pa, sa, lpv, lsv, lpa, lsa, j);

    float CinA = (j + 1 < TPB) ? lsa[j + 1] : 0.0f;
    float QrA  = (j + 1 < TPB) ? lpa[j + 1] : 1.0f;
    float chPv = lpv[0], chSv = lsv[0], chPa = lpa[0], chSa = lsa[0];

    float x = CinA, ql = 1.0f;
    float s0 = 0, s1 = 0, s2 = 0, s3 = 0, s4 = 0;
#pragma unroll
    for (int k = EPT - 1; k >= 0; --k) {
        float m = (float)mm[k];
        float aa = kGT * m;
        x = dd[k] + aa * x;
        ql *= aa;
        float q = ql * QrA;
        s0 += x; s1 += q; s2 += x * x; s3 += x * q; s4 += q * q;
    }
    s0 = wave_redf(s0); s1 = wave_redf(s1); s2 = wave_redf(s2);
    s3 = wave_redf(s3); s4 = wave_redf(s4);
    __shared__ float rb[4][5];
    int wid = j >> 6, ln = j & 63;
    if (ln == 0) { rb[wid][0]=s0; rb[wid][1]=s1; rb[wid][2]=s2; rb[wid][3]=s3; rb[wid][4]=s4; }
    __syncthreads();
    if (j == 0) {
        float t0=0,t1=0,t2=0,t3=0,t4=0;
        for (int w = 0; w < 4; ++w) { t0+=rb[w][0]; t1+=rb[w][1]; t2+=rb[w][2]; t3+=rb[w][3]; t4+=rb[w][4]; }
        ws[0*NCH+c] = chPv; ws[1*NCH+c] = chSv; ws[2*NCH+c] = chPa; ws[3*NCH+c] = chSa;
        ws[4*NCH+c] = t0;   ws[5*NCH+c] = t1;   ws[6*NCH+c] = t2;
        ws[7*NCH+c] = t3;   ws[8*NCH+c] = t4;
    }
}

__global__ __launch_bounds__(TPB) void ppo_k2_finalize(
    const float* __restrict__ r, const float* __restrict__ v,
    const int* __restrict__ mk, const float* __restrict__ ws,
    float* __restrict__ outA, float* __restrict__ outV)
{
    const int c = blockIdx.x;
    const int j = threadIdx.x;
    const int base = c * CS + j * EPT;

    __shared__ float lpv[TPB], lsv[TPB], lpa[TPB], lsa[TPB];
    __shared__ double rd[4][2];
    __shared__ float bcast[4];

    {
        float cpv[CPT], csv[CPT], cpa[CPT], csa[CPT];
        {
            float4 t;
            t = *(const float4*)(ws + 0*NCH + 4*j); cpv[0]=t.x; cpv[1]=t.y; cpv[2]=t.z; cpv[3]=t.w;
            t = *(const float4*)(ws + 1*NCH + 4*j); csv[0]=t.x; csv[1]=t.y; csv[2]=t.z; csv[3]=t.w;
            t = *(const float4*)(ws + 2*NCH + 4*j); cpa[0]=t.x; cpa[1]=t.y; cpa[2]=t.z; cpa[3]=t.w;
            t = *(const float4*)(ws + 3*NCH + 4*j); csa[0]=t.x; csa[1]=t.y; csa[2]=t.z; csa[3]=t.w;
        }
        float gpv = 1.0f, gsv = 0.0f, gpa = 1.0f, gsa = 0.0f;
#pragma unroll
        for (int i = CPT - 1; i >= 0; --i) {
            gsv = csv[i] + cpv[i] * gsv; gpv = cpv[i] * gpv;
            gsa = csa[i] + cpa[i] * gsa; gpa = cpa[i] * gpa;
        }

        block_suffix_scan(gpv, gsv, gpa, gsa, lpv, lsv, lpa, lsa, j);

        float Cv = (j + 1 < TPB) ? lsv[j + 1] : 0.0f;
        float Ca = (j + 1 < TPB) ? lsa[j + 1] : 0.0f;

        float sLv[CPT], sqv[CPT], sL2v[CPT], sLqv[CPT], sq2v[CPT];
        {
            float4 t;
            t = *(const float4*)(ws + 4*NCH + 4*j); sLv[0]=t.x;  sLv[1]=t.y;  sLv[2]=t.z;  sLv[3]=t.w;
            t = *(const float4*)(ws + 5*NCH + 4*j); sqv[0]=t.x;  sqv[1]=t.y;  sqv[2]=t.z;  sqv[3]=t.w;
            t = *(const float4*)(ws + 6*NCH + 4*j); sL2v[0]=t.x; sL2v[1]=t.y; sL2v[2]=t.z; sL2v[3]=t.w;
            t = *(const float4*)(ws + 7*NCH + 4*j); sLqv[0]=t.x; sLqv[1]=t.y; sLqv[2]=t.z; sLqv[3]=t.w;
            t = *(const float4*)(ws + 8*NCH + 4*j); sq2v[0]=t.x; sq2v[1]=t.y; sq2v[2]=t.z; sq2v[3]=t.w;
        }
        double dS = 0.0, dS2 = 0.0;
#pragma unroll
        for (int i = CPT - 1; i >= 0; --i) {
            int g = 4*j + i;
            if (g == c) { bcast[0] = Cv; bcast[1] = Ca; }
            dS  += (double)(sLv[i]  + Ca * sqv[i]);
            dS2 += (double)(sL2v[i] + 2.0f * Ca * sLqv[i] + Ca * Ca * sq2v[i]);
            Cv = csv[i] + cpv[i] * Cv;
            Ca = csa[i] + cpa[i] * Ca;
        }
        dS = wave_redd(dS); dS2 = wave_redd(dS2);
        int wid = j >> 6, ln = j & 63;
        if (ln == 0) { rd[wid][0] = dS; rd[wid][1] = dS2; }
        __syncthreads();
        if (j == 0) {
            double S  = rd[0][0] + rd[1][0] + rd[2][0] + rd[3][0];
            double S2 = rd[0][1] + rd[1][1] + rd[2][1] + rd[3][1];
            double n = (double)BTOT;
            double mean = S / n;
            double var = (S2 - S * mean) / (n - 1.0);
            bcast[2] = (float)mean;
            bcast[3] = (float)(1.0 / sqrt(var));
        }
        __syncthreads();
    }

    float rr[EPT], vv[EPT + 1], dd[EPT];
    int mm[EPT];
    const float4* r4 = (const float4*)(r + base);
    const float4* v4 = (const float4*)(v + base);
    const int4*   m4 = (const int4*)(mk + base);
#pragma unroll
    for (int k = 0; k < EPT / 4; ++k) {
        float4 a = r4[k];
        rr[4*k] = a.x; rr[4*k+1] = a.y; rr[4*k+2] = a.z; rr[4*k+3] = a.w;
        float4 b = v4[k];
        vv[4*k] = b.x; vv[4*k+1] = b.y; vv[4*k+2] = b.z; vv[4*k+3] = b.w;
        int4 m = m4[k];
        mm[4*k] = m.x; mm[4*k+1] = m.y; mm[4*k+2] = m.z; mm[4*k+3] = m.w;
    }
    vv[EPT] = (base + EPT < BTOT) ? v[base + EPT] : 0.0f;
#pragma unroll
    for (int k = 0; k < EPT; ++k) {
        float m = (float)mm[k];
        dd[k] = rr[k] + kG * m * vv[k + 1] - vv[k];
    }

    float pv = 1.0f, sv = 0.0f, pa = 1.0f, sa = 0.0f;
#pragma unroll
    for (int k = EPT - 1; k >= 0; --k) {
        float m = (float)mm[k];
        float av = kG * m, aa = kGT * m;
        sv = rr[k] + av * sv;
        sa = dd[k] + aa * sa;
        pv *= av; pa *= aa;
    }
    block_suffix_scan(pv, sv, pa, sa, lpv, lsv, lpa, lsa, j);

    float CinV = (j + 1 < TPB) ? lsv[j + 1] : 0.0f;
    float QrV  = (j + 1 < TPB) ? lpv[j + 1] : 1.0f;
    float CinA = (j + 1 < TPB) ? lsa[j + 1] : 0.0f;
    float QrA  = (j + 1 < TPB) ? lpa[j + 1] : 1.0f;

    const float Ccv  = bcast[0];
    const float Cca  = bcast[1];
    const float mean = bcast[2];
    const float inv  = bcast[3];

    float xv = CinV + QrV * Ccv;
    float xa = CinA + QrA * Cca;
    float oA[EPT], oV[EPT];
#pragma unroll
    for (int k = EPT - 1; k >= 0; --k) {
        float m = (float)mm[k];
        xv = rr[k] + kG  * m * xv;
        xa = dd[k] + kGT * m * xa;
        oV[k] = xv;
        oA[k] = (xa - mean) * inv;
    }
    float4* a4 = (float4*)(outA + base);
    float4* w4 = (float4*)(outV + base);
#pragma unroll
    for (int k = 0; k < EPT / 4; ++k) {
        a4[k] = make_float4(oA[4*k], oA[4*k+1], oA[4*k+2], oA[4*k+3]);
        w4[k] = make_float4(oV[4*k], oV[4*k+1], oV[4*k+2], oV[4*k+3]);
    }
}

extern "C" void kernel_launch(void* const* d_in, const int* in_sizes, int n_in,
                              void* d_out, int out_size, void* d_ws, size_t ws_size,
                              hipStream_t stream) {
    const float* r  = (const float*)d_in[0];
    const float* v  = (const float*)d_in[1];
    const int*   mk = (const int*)d_in[2];
    float* outA = (float*)d_out;
    float* outV = outA + BTOT;
    float* ws   = (float*)d_ws;

    void* args[6];
    args[0] = (void*)&r;    args[1] = (void*)&v;    args[2] = (void*)&mk;
    args[3] = (void*)&ws;   args[4] = (void*)&outA; args[5] = (void*)&outV;

    // Cooperative launch guarantees co-residency of all 1024 blocks (needed
    // for the hand-rolled barrier); we just don't use cg's slow sync.
    hipError_t e = hipLaunchCooperativeKernel(
        (const void*)ppo_fused, dim3(NCH), dim3(TPB), args, 0, stream);
    if (e != hipSuccess) {
        // Fallback: proven two-kernel path (implicit global sync between them)
        hipLaunchKernelGGL(ppo_k1_summarize, dim3(NCH), dim3(TPB), 0, stream,
                           r, v, mk, ws);
        hipLaunchKernelGGL(ppo_k2_finalize, dim3(NCH), dim3(TPB), 0, stream,
                           r, v, mk, ws, outA, outV);
    }
}

// Round 6
// 119.943 us; speedup vs baseline: 2.0923x; 1.2081x over previous
//
#include <hip/hip_runtime.h>
#include <math.h>

// Fixed-size problem: B = 4194304
#define BTOT 4194304
#define TPB  256
#define EPT  16                 // elements per thread
#define CS   (TPB * EPT)        // 4096 elements per chunk/block
#define NCH  (BTOT / CS)        // 1024 chunks
#define CPT  (NCH / TPB)        // 4 chunks per thread in the chunk-scan

// ws layout (float offsets):
//   WS_SUM: 9 arrays of NCH chunk summaries (Pv Sv Pa Sa sL sq sL2 sLq sq2)
//   WS_DD : dd[BTOT]            (saved deltas, K1 -> K2)
//   WS_MB : packed mask bits    (BTOT/16 uints; bit k of word (c*TPB+j))
//   WS_CAR: per-thread carries  (float4 = CinV,QrV,CinA,QrA per (c,j))
// Total ~22.1 MB << workspace size.
#define WS_SUM 0
#define WS_DD  16384
#define WS_MB  (WS_DD + BTOT)
#define WS_CAR (WS_MB + BTOT / 16)

__constant__ const float kG  = 0.99f;
__constant__ const float kGT = 0.99f * 0.95f;

__device__ __forceinline__ float wave_redf(float x) {
#pragma unroll
    for (int o = 32; o > 0; o >>= 1) x += __shfl_down(x, o);
    return x;
}
__device__ __forceinline__ double wave_redd(double x) {
#pragma unroll
    for (int o = 32; o > 0; o >>= 1) x += __shfl_down(x, o);
    return x;
}

// Hillis-Steele suffix scan over the block on affine pairs (P,S) for both
// recurrences. Entry j ends as the composition of threads j..TPB-1.
__device__ __forceinline__ void block_suffix_scan(
    float pv, float sv, float pa, float sa,
    float* lpv, float* lsv, float* lpa, float* lsa, int j)
{
    lpv[j] = pv; lsv[j] = sv; lpa[j] = pa; lsa[j] = sa;
    __syncthreads();
#pragma unroll
    for (int d = 1; d < TPB; d <<= 1) {
        float cpv = lpv[j], csv = lsv[j], cpa = lpa[j], csa = lsa[j];
        bool has = (j + d) < TPB;
        float qpv = 1.0f, qsv = 0.0f, qpa = 1.0f, qsa = 0.0f;
        if (has) { qpv = lpv[j+d]; qsv = lsv[j+d]; qpa = lpa[j+d]; qsa = lsa[j+d]; }
        __syncthreads();
        if (has) {
            lpv[j] = cpv * qpv; lsv[j] = csv + cpv * qsv;
            lpa[j] = cpa * qpa; lsa[j] = csa + cpa * qsa;
        }
        __syncthreads();
    }
}

// ---------------- K1: per-chunk summaries + save dd / mask-bits / carries --
__global__ __launch_bounds__(TPB) void ppo_k1_summarize(
    const float* __restrict__ r, const float* __restrict__ v,
    const int* __restrict__ mk, float* __restrict__ ws) {
    const int c = blockIdx.x;
    const int j = threadIdx.x;
    const int base = c * CS + j * EPT;

    float rr[EPT], vv[EPT + 1], dd[EPT];
    int mm[EPT];
    const float4* r4 = (const float4*)(r + base);
    const float4* v4 = (const float4*)(v + base);
    const int4*   m4 = (const int4*)(mk + base);
#pragma unroll
    for (int k = 0; k < EPT / 4; ++k) {
        float4 a = r4[k];
        rr[4*k] = a.x; rr[4*k+1] = a.y; rr[4*k+2] = a.z; rr[4*k+3] = a.w;
        float4 b = v4[k];
        vv[4*k] = b.x; vv[4*k+1] = b.y; vv[4*k+2] = b.z; vv[4*k+3] = b.w;
        int4 m = m4[k];
        mm[4*k] = m.x; mm[4*k+1] = m.y; mm[4*k+2] = m.z; mm[4*k+3] = m.w;
    }
    vv[EPT] = (base + EPT < BTOT) ? v[base + EPT] : 0.0f;

    unsigned mb = 0;
#pragma unroll
    for (int k = 0; k < EPT; ++k) {
        mb |= ((unsigned)(mm[k] & 1)) << k;
        float m = (float)mm[k];
        dd[k] = rr[k] + kG * m * vv[k + 1] - vv[k];
    }

    // save dd (float4) + packed mask bits for K2 (skips v re-read + recompute)
    {
        float4* d4 = (float4*)(ws + WS_DD + base);
#pragma unroll
        for (int k = 0; k < EPT / 4; ++k)
            d4[k] = make_float4(dd[4*k], dd[4*k+1], dd[4*k+2], dd[4*k+3]);
        ((unsigned*)(ws + WS_MB))[c * TPB + j] = mb;
    }

    // per-thread affine summaries (reverse, zero carry)
    float pv = 1.0f, sv = 0.0f, pa = 1.0f, sa = 0.0f;
#pragma unroll
    for (int k = EPT - 1; k >= 0; --k) {
        float m = (float)mm[k];
        float av = kG * m, aa = kGT * m;
        sv = rr[k] + av * sv;
        sa = dd[k] + aa * sa;
        pv *= av; pa *= aa;
    }

    __shared__ float lpv[TPB], lsv[TPB], lpa[TPB], lsa[TPB];
    block_suffix_scan(pv, sv, pa, sa, lpv, lsv, lpa, lsa, j);

    float CinV = (j + 1 < TPB) ? lsv[j + 1] : 0.0f;
    float QrV  = (j + 1 < TPB) ? lpv[j + 1] : 1.0f;
    float CinA = (j + 1 < TPB) ? lsa[j + 1] : 0.0f;
    float QrA  = (j + 1 < TPB) ? lpa[j + 1] : 1.0f;
    float chPv = lpv[0], chSv = lsv[0], chPa = lpa[0], chSa = lsa[0];

    // save per-thread carries so K2 skips the per-chunk block scan entirely
    *(float4*)(ws + WS_CAR + 4 * (c * TPB + j)) =
        make_float4(CinV, QrV, CinA, QrA);

    // chunk-local A values + quadratic stats: A = L + q * C_chunk
    float x = CinA, ql = 1.0f;
    float s0 = 0, s1 = 0, s2 = 0, s3 = 0, s4 = 0;
#pragma unroll
    for (int k = EPT - 1; k >= 0; --k) {
        float m = (float)mm[k];
        float aa = kGT * m;
        x = dd[k] + aa * x;
        ql *= aa;
        float q = ql * QrA;
        s0 += x; s1 += q; s2 += x * x; s3 += x * q; s4 += q * q;
    }
    s0 = wave_redf(s0); s1 = wave_redf(s1); s2 = wave_redf(s2);
    s3 = wave_redf(s3); s4 = wave_redf(s4);
    __shared__ float rb[4][5];
    int wid = j >> 6, ln = j & 63;
    if (ln == 0) { rb[wid][0]=s0; rb[wid][1]=s1; rb[wid][2]=s2; rb[wid][3]=s3; rb[wid][4]=s4; }
    __syncthreads();
    if (j == 0) {
        float t0=0,t1=0,t2=0,t3=0,t4=0;
        for (int w = 0; w < 4; ++w) { t0+=rb[w][0]; t1+=rb[w][1]; t2+=rb[w][2]; t3+=rb[w][3]; t4+=rb[w][4]; }
        ws[0*NCH+c] = chPv; ws[1*NCH+c] = chSv; ws[2*NCH+c] = chPa; ws[3*NCH+c] = chSa;
        ws[4*NCH+c] = t0;   ws[5*NCH+c] = t1;   ws[6*NCH+c] = t2;
        ws[7*NCH+c] = t3;   ws[8*NCH+c] = t4;
    }
}

// ------- K2: redundant chunk-summary scan + finalize from saved state ------
__global__ __launch_bounds__(TPB) void ppo_k2_finalize(
    const float* __restrict__ r, const float* __restrict__ ws,
    float* __restrict__ outA, float* __restrict__ outV)
{
    const int c = blockIdx.x;
    const int j = threadIdx.x;
    const int base = c * CS + j * EPT;

    __shared__ float lpv[TPB], lsv[TPB], lpa[TPB], lsa[TPB];
    __shared__ double rd[4][2];
    __shared__ float bcast[4];   // 0:carryV(into chunk c) 1:carryA 2:mean 3:inv_std

    // ---- redundant chunk-summary scan (identical in every block) ----
    {
        float cpv[CPT], csv[CPT], cpa[CPT], csa[CPT];
        {
            float4 t;
            t = *(const float4*)(ws + 0*NCH + 4*j); cpv[0]=t.x; cpv[1]=t.y; cpv[2]=t.z; cpv[3]=t.w;
            t = *(const float4*)(ws + 1*NCH + 4*j); csv[0]=t.x; csv[1]=t.y; csv[2]=t.z; csv[3]=t.w;
            t = *(const float4*)(ws + 2*NCH + 4*j); cpa[0]=t.x; cpa[1]=t.y; cpa[2]=t.z; cpa[3]=t.w;
            t = *(const float4*)(ws + 3*NCH + 4*j); csa[0]=t.x; csa[1]=t.y; csa[2]=t.z; csa[3]=t.w;
        }
        float gpv = 1.0f, gsv = 0.0f, gpa = 1.0f, gsa = 0.0f;
#pragma unroll
        for (int i = CPT - 1; i >= 0; --i) {
            gsv = csv[i] + cpv[i] * gsv; gpv = cpv[i] * gpv;
            gsa = csa[i] + cpa[i] * gsa; gpa = cpa[i] * gpa;
        }

        block_suffix_scan(gpv, gsv, gpa, gsa, lpv, lsv, lpa, lsa, j);

        float Cv = (j + 1 < TPB) ? lsv[j + 1] : 0.0f;
        float Ca = (j + 1 < TPB) ? lsa[j + 1] : 0.0f;

        float sLv[CPT], sqv[CPT], sL2v[CPT], sLqv[CPT], sq2v[CPT];
        {
            float4 t;
            t = *(const float4*)(ws + 4*NCH + 4*j); sLv[0]=t.x;  sLv[1]=t.y;  sLv[2]=t.z;  sLv[3]=t.w;
            t = *(const float4*)(ws + 5*NCH + 4*j); sqv[0]=t.x;  sqv[1]=t.y;  sqv[2]=t.z;  sqv[3]=t.w;
            t = *(const float4*)(ws + 6*NCH + 4*j); sL2v[0]=t.x; sL2v[1]=t.y; sL2v[2]=t.z; sL2v[3]=t.w;
            t = *(const float4*)(ws + 7*NCH + 4*j); sLqv[0]=t.x; sLqv[1]=t.y; sLqv[2]=t.z; sLqv[3]=t.w;
            t = *(const float4*)(ws + 8*NCH + 4*j); sq2v[0]=t.x; sq2v[1]=t.y; sq2v[2]=t.z; sq2v[3]=t.w;
        }
        double dS = 0.0, dS2 = 0.0;
#pragma unroll
        for (int i = CPT - 1; i >= 0; --i) {
            int g = 4*j + i;
            if (g == c) { bcast[0] = Cv; bcast[1] = Ca; }   // carry INTO our chunk
            dS  += (double)(sLv[i]  + Ca * sqv[i]);
            dS2 += (double)(sL2v[i] + 2.0f * Ca * sLqv[i] + Ca * Ca * sq2v[i]);
            Cv = csv[i] + cpv[i] * Cv;
            Ca = csa[i] + cpa[i] * Ca;
        }
        dS = wave_redd(dS); dS2 = wave_redd(dS2);
        int wid = j >> 6, ln = j & 63;
        if (ln == 0) { rd[wid][0] = dS; rd[wid][1] = dS2; }
        __syncthreads();
        if (j == 0) {
            double S  = rd[0][0] + rd[1][0] + rd[2][0] + rd[3][0];
            double S2 = rd[0][1] + rd[1][1] + rd[2][1] + rd[3][1];
            double n = (double)BTOT;
            double mean = S / n;
            double var = (S2 - S * mean) / (n - 1.0);   // ddof=1
            bcast[2] = (float)mean;
            bcast[3] = (float)(1.0 / sqrt(var));
        }
        __syncthreads();
    }

    // ---- finalize from saved state: r + dd + mask-bits + carries ----
    // (no v read, no delta recompute, no second block scan)
    float rr[EPT], dd[EPT];
    {
        const float4* r4 = (const float4*)(r + base);
        const float4* d4 = (const float4*)(ws + WS_DD + base);
#pragma unroll
        for (int k = 0; k < EPT / 4; ++k) {
            float4 a = r4[k];
            rr[4*k] = a.x; rr[4*k+1] = a.y; rr[4*k+2] = a.z; rr[4*k+3] = a.w;
            float4 b = d4[k];
            dd[4*k] = b.x; dd[4*k+1] = b.y; dd[4*k+2] = b.z; dd[4*k+3] = b.w;
        }
    }
    const unsigned mb = ((const unsigned*)(ws + WS_MB))[c * TPB + j];
    const float4 car = *(const float4*)(ws + WS_CAR + 4 * (c * TPB + j));

    const float Ccv  = bcast[0];
    const float Cca  = bcast[1];
    const float mean = bcast[2];
    const float inv  = bcast[3];

    float xv = car.x + car.y * Ccv;   // CinV + QrV * carry
    float xa = car.z + car.w * Cca;   // CinA + QrA * carry
    float oA[EPT], oV[EPT];
#pragma unroll
    for (int k = EPT - 1; k >= 0; --k) {
        float m = (float)((mb >> k) & 1u);
        xv = rr[k] + kG  * m * xv;
        xa = dd[k] + kGT * m * xa;
        oV[k] = xv;
        oA[k] = (xa - mean) * inv;
    }
    float4* a4 = (float4*)(outA + base);
    float4* w4 = (float4*)(outV + base);
#pragma unroll
    for (int k = 0; k < EPT / 4; ++k) {
        a4[k] = make_float4(oA[4*k], oA[4*k+1], oA[4*k+2], oA[4*k+3]);
        w4[k] = make_float4(oV[4*k], oV[4*k+1], oV[4*k+2], oV[4*k+3]);
    }
}

extern "C" void kernel_launch(void* const* d_in, const int* in_sizes, int n_in,
                              void* d_out, int out_size, void* d_ws, size_t ws_size,
                              hipStream_t stream) {
    const float* r  = (const float*)d_in[0];
    const float* v  = (const float*)d_in[1];
    const int*   mk = (const int*)d_in[2];
    float* outA = (float*)d_out;
    float* outV = outA + BTOT;
    float* ws   = (float*)d_ws;

    hipLaunchKernelGGL(ppo_k1_summarize, dim3(NCH), dim3(TPB), 0, stream,
                       r, v, mk, ws);
    hipLaunchKernelGGL(ppo_k2_finalize, dim3(NCH), dim3(TPB), 0, stream,
                       r, ws, outA, outV);
}